// Round 16
// baseline (63.837 us; speedup 1.0000x reference)
//
#include <hip/hip_runtime.h>
#include <math.h>

// Problem constants (match reference)
constexpr int B = 8, S = 128, T = 4096;
constexpr int NPIX = 256 * 256;          // NX*NY
constexpr float RVS = 1.0f / 1550.0f;    // compile-time correctly-rounded f32
constexpr float RDT = 1.0e7f;            // fl32(1/fl32(1e-7)) == 1e7 (exact)
constexpr int NCHUNK = 8;                // sensor chunks == XCD count
constexpr int SCHUNK = S / NCHUNK;       // 16 sensors per chunk
constexpr int TT = 2336;                 // t_max=2326 -> only transpose t<TT (x4 aligned)
constexpr size_t DT_BYTES   = (size_t)S * TT * B * sizeof(float);     // ~9.1 MB
constexpr size_t PART_BYTES = (size_t)NPIX * B * sizeof(float);       // 2 MB
constexpr size_t MM_OFF     = DT_BYTES + NCHUNK * PART_BYTES;         // ~25.1 MB
constexpr size_t WS_NEED    = MM_OFF + 256;
constexpr int FIN_BLOCKS = (B * NPIX) / 1024;   // 512 blocks (2/CU -> co-resident)

// Verified t-chain (round 11, absmax 0.0039): XLA f32 with x/const -> x*(1/const).
__device__ __forceinline__ int tof_index(int dxi, int dyi) {
    float ax = (float)dxi * 1e-3f;
    float ay = (float)dyi * 1e-3f;
    float px = ax * ax;
    float py = ay * ay;
    asm volatile("" : "+v"(px));         // pin rounded squares: forbid FMA
    asm volatile("" : "+v"(py));
    float d2  = px + py;
    float dis = __fsqrt_rn(d2);
    float q1  = __fmul_rn(dis, RVS);
    asm volatile("" : "+v"(q1));
    float tf  = __fmul_rn(q1, RDT);
    return (int)tf;                      // t_max == 2326 < TT
}

// Orderable uint mapping for float min/max atomics (monotonic, bijective).
__device__ __forceinline__ unsigned fkey(float f) {
    unsigned u = __float_as_uint(f);
    return ((int)u < 0) ? ~u : (u | 0x80000000u);
}
__device__ __forceinline__ float funkey(unsigned k) {
    return __uint_as_float(((int)k < 0) ? (k ^ 0x80000000u) : ~k);
}

// ---------- fast path ----------

// Transpose (B,S,t<TT) -> (S,TT,B), 4 t-elements per thread (128B writes).
// Block 0 also re-initializes the min/max atomic keys + barrier counter.
__global__ __launch_bounds__(256) void das_transpose(const float* __restrict__ data,
                                                     float* __restrict__ dt,
                                                     unsigned* __restrict__ mm) {
    int tid = threadIdx.x;
    if (blockIdx.x == 0 && tid < 17)
        mm[tid] = (tid < 8) ? 0xFFFFFFFFu : 0u;   // min-keys, max-keys, counter
    int i  = blockIdx.x * 256 + tid;              // over S * TT/4
    int s  = i / (TT / 4);
    int t0 = (i - s * (TT / 4)) * 4;
    const float* src = data + (size_t)s * T + t0;
    float4 v[B];
#pragma unroll
    for (int b = 0; b < B; ++b)
        v[b] = *(const float4*)(src + (size_t)b * (S * T));
    float* o = dt + ((size_t)s * TT + t0) * B;
#pragma unroll
    for (int j = 0; j < 4; ++j) {
        float4 lo = make_float4((&v[0].x)[j], (&v[1].x)[j], (&v[2].x)[j], (&v[3].x)[j]);
        float4 hi = make_float4((&v[4].x)[j], (&v[5].x)[j], (&v[6].x)[j], (&v[7].x)[j]);
        *(float4*)(o + j * B)     = lo;
        *(float4*)(o + j * B + 4) = hi;
    }
}

// Delay-and-sum: one thread per pixel, 8 fp32 batch accumulators, 8x8 pixel
// tile per wave (t-span per gather ~70 rows -> few L2 lines). Chunk k -> XCD k
// via round-robin dispatch (bid&7); hot dt slice ~1.1MB/XCD stays L2-resident;
// partial stores are non-temporal to avoid evicting it.
__global__ __launch_bounds__(256, 8) void das_accum8(const float* __restrict__ dt,
                                                     const int* __restrict__ sxy,
                                                     float* __restrict__ part) {
    unsigned bid = blockIdx.x;
    int chunk = bid & 7;                          // -> XCD chunk
    int tile  = bid >> 3;                         // 0..255 (16x16 tile grid)
    int tid   = threadIdx.x;
    int l = tid & 63, w = tid >> 6;
    int ix = ((tile >> 4) << 4) + ((w >> 1) << 3) + (l >> 3);
    int iy = ((tile & 15) << 4) + ((w & 1) << 3) + (l & 7);
    int p  = (ix << 8) + iy;

    float acc[B];
#pragma unroll
    for (int b = 0; b < B; ++b) acc[b] = 0.0f;

    int s0 = chunk * SCHUNK;
#pragma unroll
    for (int k = 0; k < SCHUNK; ++k) {
        int s = s0 + k;
        int dxi = abs(sxy[2 * s] - ix);           // sxy: uniform s_load
        int dyi = abs(sxy[2 * s + 1] - iy);
        int t = tof_index(dxi, dyi);
        const float4* row = (const float4*)(dt + (((size_t)s * TT + t) << 3));
        float4 lo = row[0];
        float4 hi = row[1];
        acc[0] += lo.x; acc[1] += lo.y; acc[2] += lo.z; acc[3] += lo.w;
        acc[4] += hi.x; acc[5] += hi.y; acc[6] += hi.z; acc[7] += hi.w;
    }

    float* dst = part + (size_t)chunk * NPIX * B;
#pragma unroll
    for (int b = 0; b < B; ++b)
        __builtin_nontemporal_store(acc[b], dst + b * NPIX + p);
}

// Fused combine + per-batch min/max + normalize. 512 blocks (co-resident at
// 2 blocks/CU) with a light internal grid barrier: only the 64B mm array
// crosses blocks; each block's pixel sums stay in registers across the
// barrier, and `out` is written exactly once.
__global__ __launch_bounds__(256) void das_finish(const float* __restrict__ part,
                                                  float* __restrict__ out,
                                                  unsigned* __restrict__ mm) {
    size_t i4 = ((size_t)blockIdx.x * 256 + threadIdx.x) * 4;
    int b = (int)(i4 >> 16);

    float4 v = make_float4(0.f, 0.f, 0.f, 0.f);
#pragma unroll
    for (int c = 0; c < NCHUNK; ++c) {
        const float* q = part + (size_t)c * NPIX * B + i4;
        v.x += __builtin_nontemporal_load(q);
        v.y += __builtin_nontemporal_load(q + 1);
        v.z += __builtin_nontemporal_load(q + 2);
        v.w += __builtin_nontemporal_load(q + 3);
    }

    float mn = fminf(fminf(v.x, v.y), fminf(v.z, v.w));
    float mx = fmaxf(fmaxf(v.x, v.y), fmaxf(v.z, v.w));
    for (int off = 32; off; off >>= 1) {
        mn = fminf(mn, __shfl_down(mn, off));
        mx = fmaxf(mx, __shfl_down(mx, off));
    }
    __shared__ float smn[4], smx[4];
    int w = threadIdx.x >> 6;
    if ((threadIdx.x & 63) == 0) { smn[w] = mn; smx[w] = mx; }
    __syncthreads();
    if (threadIdx.x == 0) {
        mn = fminf(fminf(smn[0], smn[1]), fminf(smn[2], smn[3]));
        mx = fmaxf(fmaxf(smx[0], smx[1]), fmaxf(smx[2], smx[3]));
        __hip_atomic_fetch_min(&mm[b], fkey(mn),
                               __ATOMIC_RELAXED, __HIP_MEMORY_SCOPE_AGENT);
        __hip_atomic_fetch_max(&mm[8 + b], fkey(mx),
                               __ATOMIC_RELAXED, __HIP_MEMORY_SCOPE_AGENT);
        // arrive (release) ... wait (acquire): synchronizes the mm atomics
        __hip_atomic_fetch_add(&mm[16], 1u,
                               __ATOMIC_ACQ_REL, __HIP_MEMORY_SCOPE_AGENT);
        while (__hip_atomic_load(&mm[16], __ATOMIC_ACQUIRE,
                                 __HIP_MEMORY_SCOPE_AGENT) < (unsigned)FIN_BLOCKS)
            __builtin_amdgcn_s_sleep(1);
    }
    __syncthreads();

    float fmn = funkey(mm[b]);
    float rs  = __fsub_rn(funkey(mm[8 + b]), fmn);
    v.x = __fdiv_rn(__fsub_rn(v.x, fmn), rs);
    v.y = __fdiv_rn(__fsub_rn(v.y, fmn), rs);
    v.z = __fdiv_rn(__fsub_rn(v.z, fmn), rs);
    v.w = __fdiv_rn(__fsub_rn(v.w, fmn), rs);
    *(float4*)(out + i4) = v;
}

// ---------- fallback path (round-12, proven, needs 128KB ws) ----------

__global__ __launch_bounds__(256) void build_tab(unsigned short* __restrict__ tab) {
    int i = blockIdx.x * 256 + threadIdx.x;
    tab[i] = (unsigned short)tof_index(i >> 8, i & 255);
}

__global__ __launch_bounds__(256) void das_accum(const float* __restrict__ data,
                                                 const int* __restrict__ sxy,
                                                 const unsigned short* __restrict__ tab,
                                                 float* __restrict__ out) {
    __shared__ int sx[S], sy[S];
    int tid = threadIdx.x;
    if (tid < S) { sx[tid] = sxy[2 * tid]; sy[tid] = sxy[2 * tid + 1]; }
    __syncthreads();
    int b = blockIdx.x >> 8, ix = blockIdx.x & 255, iy = tid;
    int p = (ix << 8) + iy;
    const float* dbase = data + b * (S * T);
    double acc = 0.0;
#pragma unroll 8
    for (int s = 0; s < S; ++s) {
        int t = (int)tab[(abs(sx[s] - ix) << 8) + abs(sy[s] - iy)];
        acc += (double)dbase[s * T + t];
    }
    out[b * NPIX + p] = (float)acc;
}

__global__ __launch_bounds__(1024) void das_minmax(const float* __restrict__ img,
                                                   float* __restrict__ mmf) {
    int b = blockIdx.x;
    const float* p = img + b * NPIX;
    float mn = 3.0e38f, mx = -3.0e38f;
    for (int i = threadIdx.x; i < NPIX; i += 1024) {
        float v = p[i];
        mn = fminf(mn, v); mx = fmaxf(mx, v);
    }
    for (int off = 32; off; off >>= 1) {
        mn = fminf(mn, __shfl_down(mn, off));
        mx = fmaxf(mx, __shfl_down(mx, off));
    }
    __shared__ float smn[16], smx[16];
    int w = threadIdx.x >> 6;
    if ((threadIdx.x & 63) == 0) { smn[w] = mn; smx[w] = mx; }
    __syncthreads();
    if (threadIdx.x < 16) {
        mn = smn[threadIdx.x]; mx = smx[threadIdx.x];
        for (int off = 8; off; off >>= 1) {
            mn = fminf(mn, __shfl_down(mn, off));
            mx = fmaxf(mx, __shfl_down(mx, off));
        }
        if (threadIdx.x == 0) { mmf[2 * b] = mn; mmf[2 * b + 1] = mx; }
    }
}

__global__ __launch_bounds__(256) void das_norm(float* __restrict__ out,
                                                const float* __restrict__ mmf) {
    int i = blockIdx.x * 256 + threadIdx.x;
    int b = i >> 16;
    out[i] = __fdiv_rn(__fsub_rn(out[i], mmf[2 * b]), __fsub_rn(mmf[2 * b + 1], mmf[2 * b]));
}

extern "C" void kernel_launch(void* const* d_in, const int* in_sizes, int n_in,
                              void* d_out, int out_size, void* d_ws, size_t ws_size,
                              hipStream_t stream) {
    const float* data = (const float*)d_in[0];   // (B, S, T) fp32
    const int*   sxy  = (const int*)d_in[1];     // (S, 2) int32
    float* out = (float*)d_out;                  // (B, 256, 256) fp32

    if (ws_size >= WS_NEED) {
        float*    dt   = (float*)d_ws;
        float*    part = (float*)((char*)d_ws + DT_BYTES);
        unsigned* mm   = (unsigned*)((char*)d_ws + MM_OFF);
        das_transpose<<<(S * TT) / 1024, 256, 0, stream>>>(data, dt, mm);
        das_accum8<<<NCHUNK * 256, 256, 0, stream>>>(dt, sxy, part);
        das_finish<<<FIN_BLOCKS, 256, 0, stream>>>(part, out, mm);
    } else {
        unsigned short* tab = (unsigned short*)d_ws;
        float* mmf = (float*)((char*)d_ws + NPIX * sizeof(unsigned short));
        build_tab<<<NPIX / 256, 256, 0, stream>>>(tab);
        das_accum<<<B * 256, 256, 0, stream>>>(data, sxy, tab, out);
        das_minmax<<<B, 1024, 0, stream>>>(out, mmf);
        das_norm<<<(B * NPIX) / 256, 256, 0, stream>>>(out, mmf);
    }
}

// Round 18
// 49.905 us; speedup vs baseline: 1.2792x; 1.2792x over previous
//
#include <hip/hip_runtime.h>
#include <math.h>

// Problem constants (match reference)
constexpr int B = 8, S = 128, T = 4096;
constexpr int NPIX = 256 * 256;          // NX*NY
constexpr float RVS = 1.0f / 1550.0f;    // compile-time correctly-rounded f32
constexpr float RDT = 1.0e7f;            // fl32(1/fl32(1e-7)) == 1e7 (exact)
constexpr int NCHUNK = 8;                // sensor chunks == XCD count
constexpr int SCHUNK = S / NCHUNK;       // 16 sensors per chunk
constexpr int TT = 2336;                 // t_max=2326 -> only transpose t<TT (x4 aligned)
constexpr size_t DT_BYTES   = (size_t)S * TT * B * sizeof(float);     // ~9.1 MB
constexpr size_t PART_BYTES = (size_t)NPIX * B * sizeof(float);       // 2 MB
constexpr size_t MM_OFF     = DT_BYTES + (NCHUNK - 1) * PART_BYTES;   // ~23 MB
constexpr size_t WS_NEED    = MM_OFF + 256;

// Verified t-chain (round 11, absmax 0.0039): XLA f32 with x/const -> x*(1/const).
__device__ __forceinline__ int tof_index(int dxi, int dyi) {
    float ax = (float)dxi * 1e-3f;
    float ay = (float)dyi * 1e-3f;
    float px = ax * ax;
    float py = ay * ay;
    asm volatile("" : "+v"(px));         // pin rounded squares: forbid FMA
    asm volatile("" : "+v"(py));
    float d2  = px + py;
    float dis = __fsqrt_rn(d2);
    float q1  = __fmul_rn(dis, RVS);
    asm volatile("" : "+v"(q1));
    float tf  = __fmul_rn(q1, RDT);
    return (int)tf;                      // t_max == 2326 < TT
}

// Orderable uint mapping for float min/max atomics (monotonic, bijective).
__device__ __forceinline__ unsigned fkey(float f) {
    unsigned u = __float_as_uint(f);
    return ((int)u < 0) ? ~u : (u | 0x80000000u);
}
__device__ __forceinline__ float funkey(unsigned k) {
    return __uint_as_float(((int)k < 0) ? (k ^ 0x80000000u) : ~k);
}

// ---------- fast path ----------

// Transpose (B,S,t<TT) -> (S,TT,B), 4 t-elements per thread (128B writes).
// Block 0 also re-initializes the min/max atomic keys.
__global__ __launch_bounds__(256) void das_transpose(const float* __restrict__ data,
                                                     float* __restrict__ dt,
                                                     unsigned* __restrict__ mm) {
    int tid = threadIdx.x;
    if (blockIdx.x == 0 && tid < 16)
        mm[tid] = (tid < 8) ? 0xFFFFFFFFu : 0u;   // min-keys, max-keys
    int i  = blockIdx.x * 256 + tid;              // over S * TT/4
    int s  = i / (TT / 4);
    int t0 = (i - s * (TT / 4)) * 4;
    const float* src = data + (size_t)s * T + t0;
    float4 v[B];
#pragma unroll
    for (int b = 0; b < B; ++b)
        v[b] = *(const float4*)(src + (size_t)b * (S * T));
    float* o = dt + ((size_t)s * TT + t0) * B;
#pragma unroll
    for (int j = 0; j < 4; ++j) {
        float4 lo = make_float4((&v[0].x)[j], (&v[1].x)[j], (&v[2].x)[j], (&v[3].x)[j]);
        float4 hi = make_float4((&v[4].x)[j], (&v[5].x)[j], (&v[6].x)[j], (&v[7].x)[j]);
        *(float4*)(o + j * B)     = lo;
        *(float4*)(o + j * B + 4) = hi;
    }
}

// Delay-and-sum: one thread per pixel, 8 fp32 batch accumulators, 8x8 pixel
// tile per wave (t-span per gather ~70 rows -> few L2 lines). Chunk k -> XCD k
// via round-robin dispatch (bid&7); hot dt slice ~1.1MB/XCD stays L2-resident;
// partial stores are non-temporal to avoid evicting it.
__global__ __launch_bounds__(256, 8) void das_accum8(const float* __restrict__ dt,
                                                     const int* __restrict__ sxy,
                                                     float* __restrict__ out,
                                                     float* __restrict__ part) {
    unsigned bid = blockIdx.x;
    int chunk = bid & 7;                          // -> XCD chunk
    int tile  = bid >> 3;                         // 0..255 (16x16 tile grid)
    int tid   = threadIdx.x;
    int l = tid & 63, w = tid >> 6;
    int ix = ((tile >> 4) << 4) + ((w >> 1) << 3) + (l >> 3);
    int iy = ((tile & 15) << 4) + ((w & 1) << 3) + (l & 7);
    int p  = (ix << 8) + iy;

    float acc[B];
#pragma unroll
    for (int b = 0; b < B; ++b) acc[b] = 0.0f;

    int s0 = chunk * SCHUNK;
#pragma unroll
    for (int k = 0; k < SCHUNK; ++k) {
        int s = s0 + k;
        int dxi = abs(sxy[2 * s] - ix);           // sxy: uniform s_load
        int dyi = abs(sxy[2 * s + 1] - iy);
        int t = tof_index(dxi, dyi);
        const float4* row = (const float4*)(dt + (((size_t)s * TT + t) << 3));
        float4 lo = row[0];
        float4 hi = row[1];
        acc[0] += lo.x; acc[1] += lo.y; acc[2] += lo.z; acc[3] += lo.w;
        acc[4] += hi.x; acc[5] += hi.y; acc[6] += hi.z; acc[7] += hi.w;
    }

    float* dst = (chunk == 0) ? out : (part + (size_t)(chunk - 1) * NPIX * B);
#pragma unroll
    for (int b = 0; b < B; ++b)
        __builtin_nontemporal_store(acc[b], dst + b * NPIX + p);
}

// Combine the 8 chunk partials into out AND per-batch min/max (atomic keys).
// 4 pixels/thread; each block spans 1024 consecutive pixels of ONE batch.
__global__ __launch_bounds__(256) void das_combine(const float* __restrict__ part,
                                                   float* __restrict__ out,
                                                   unsigned* __restrict__ mm) {
    size_t i4 = ((size_t)blockIdx.x * 256 + threadIdx.x) * 4;
    int b = (int)(i4 >> 16);
    float4 v = *(float4*)(out + i4);
#pragma unroll
    for (int c = 0; c < NCHUNK - 1; ++c) {
        const float* q = part + (size_t)c * NPIX * B + i4;
        v.x += __builtin_nontemporal_load(q);
        v.y += __builtin_nontemporal_load(q + 1);
        v.z += __builtin_nontemporal_load(q + 2);
        v.w += __builtin_nontemporal_load(q + 3);
    }
    *(float4*)(out + i4) = v;

    float mn = fminf(fminf(v.x, v.y), fminf(v.z, v.w));
    float mx = fmaxf(fmaxf(v.x, v.y), fmaxf(v.z, v.w));
    for (int off = 32; off; off >>= 1) {
        mn = fminf(mn, __shfl_down(mn, off));
        mx = fmaxf(mx, __shfl_down(mx, off));
    }
    __shared__ float smn[4], smx[4];
    int w = threadIdx.x >> 6;
    if ((threadIdx.x & 63) == 0) { smn[w] = mn; smx[w] = mx; }
    __syncthreads();
    if (threadIdx.x == 0) {
        mn = fminf(fminf(smn[0], smn[1]), fminf(smn[2], smn[3]));
        mx = fmaxf(fmaxf(smx[0], smx[1]), fmaxf(smx[2], smx[3]));
        atomicMin(&mm[b], fkey(mn));
        atomicMax(&mm[8 + b], fkey(mx));
    }
}

// Per-batch min-max normalization, 4 pixels/thread, in place.
__global__ __launch_bounds__(256) void das_norm3(float* __restrict__ out,
                                                 const unsigned* __restrict__ mm) {
    size_t i4 = ((size_t)blockIdx.x * 256 + threadIdx.x) * 4;
    int b = (int)(i4 >> 16);
    float mn = funkey(mm[b]);
    float rs = __fsub_rn(funkey(mm[8 + b]), mn);
    float4 v = *(float4*)(out + i4);
    v.x = __fdiv_rn(__fsub_rn(v.x, mn), rs);
    v.y = __fdiv_rn(__fsub_rn(v.y, mn), rs);
    v.z = __fdiv_rn(__fsub_rn(v.z, mn), rs);
    v.w = __fdiv_rn(__fsub_rn(v.w, mn), rs);
    *(float4*)(out + i4) = v;
}

// ---------- fallback path (round-12, proven, needs 128KB ws) ----------

__global__ __launch_bounds__(256) void build_tab(unsigned short* __restrict__ tab) {
    int i = blockIdx.x * 256 + threadIdx.x;
    tab[i] = (unsigned short)tof_index(i >> 8, i & 255);
}

__global__ __launch_bounds__(256) void das_accum(const float* __restrict__ data,
                                                 const int* __restrict__ sxy,
                                                 const unsigned short* __restrict__ tab,
                                                 float* __restrict__ out) {
    __shared__ int sx[S], sy[S];
    int tid = threadIdx.x;
    if (tid < S) { sx[tid] = sxy[2 * tid]; sy[tid] = sxy[2 * tid + 1]; }
    __syncthreads();
    int b = blockIdx.x >> 8, ix = blockIdx.x & 255, iy = tid;
    int p = (ix << 8) + iy;
    const float* dbase = data + b * (S * T);
    double acc = 0.0;
#pragma unroll 8
    for (int s = 0; s < S; ++s) {
        int t = (int)tab[(abs(sx[s] - ix) << 8) + abs(sy[s] - iy)];
        acc += (double)dbase[s * T + t];
    }
    out[b * NPIX + p] = (float)acc;
}

__global__ __launch_bounds__(1024) void das_minmax(const float* __restrict__ img,
                                                   float* __restrict__ mmf) {
    int b = blockIdx.x;
    const float* p = img + b * NPIX;
    float mn = 3.0e38f, mx = -3.0e38f;
    for (int i = threadIdx.x; i < NPIX; i += 1024) {
        float v = p[i];
        mn = fminf(mn, v); mx = fmaxf(mx, v);
    }
    for (int off = 32; off; off >>= 1) {
        mn = fminf(mn, __shfl_down(mn, off));
        mx = fmaxf(mx, __shfl_down(mx, off));
    }
    __shared__ float smn[16], smx[16];
    int w = threadIdx.x >> 6;
    if ((threadIdx.x & 63) == 0) { smn[w] = mn; smx[w] = mx; }
    __syncthreads();
    if (threadIdx.x < 16) {
        mn = smn[threadIdx.x]; mx = smx[threadIdx.x];
        for (int off = 8; off; off >>= 1) {
            mn = fminf(mn, __shfl_down(mn, off));
            mx = fmaxf(mx, __shfl_down(mx, off));
        }
        if (threadIdx.x == 0) { mmf[2 * b] = mn; mmf[2 * b + 1] = mx; }
    }
}

__global__ __launch_bounds__(256) void das_norm(float* __restrict__ out,
                                                const float* __restrict__ mmf) {
    int i = blockIdx.x * 256 + threadIdx.x;
    int b = i >> 16;
    out[i] = __fdiv_rn(__fsub_rn(out[i], mmf[2 * b]), __fsub_rn(mmf[2 * b + 1], mmf[2 * b]));
}

extern "C" void kernel_launch(void* const* d_in, const int* in_sizes, int n_in,
                              void* d_out, int out_size, void* d_ws, size_t ws_size,
                              hipStream_t stream) {
    const float* data = (const float*)d_in[0];   // (B, S, T) fp32
    const int*   sxy  = (const int*)d_in[1];     // (S, 2) int32
    float* out = (float*)d_out;                  // (B, 256, 256) fp32

    if (ws_size >= WS_NEED) {
        float*    dt   = (float*)d_ws;
        float*    part = (float*)((char*)d_ws + DT_BYTES);
        unsigned* mm   = (unsigned*)((char*)d_ws + MM_OFF);
        das_transpose<<<(S * TT) / 1024, 256, 0, stream>>>(data, dt, mm);
        das_accum8<<<NCHUNK * 256, 256, 0, stream>>>(dt, sxy, out, part);
        das_combine<<<(B * NPIX) / 1024, 256, 0, stream>>>(part, out, mm);
        das_norm3<<<(B * NPIX) / 1024, 256, 0, stream>>>(out, mm);
    } else {
        unsigned short* tab = (unsigned short*)d_ws;
        float* mmf = (float*)((char*)d_ws + NPIX * sizeof(unsigned short));
        build_tab<<<NPIX / 256, 256, 0, stream>>>(tab);
        das_accum<<<B * 256, 256, 0, stream>>>(data, sxy, tab, out);
        das_minmax<<<B, 1024, 0, stream>>>(out, mmf);
        das_norm<<<(B * NPIX) / 256, 256, 0, stream>>>(out, mmf);
    }
}